// Round 16
// baseline (85.272 us; speedup 1.0000x reference)
//
#include <hip/hip_runtime.h>
#include <math.h>

#define AFWD 0.999f
#define ONE_MINUS_A (1.0f - 0.999f)
#define KCOEF (0.999f * (1.0f - 0.999f))
#define EPSV 1e-5f

typedef float floatx4 __attribute__((ext_vector_type(4)));

// ===========================================================================
// Two-dispatch online normalization.
// D1 (passA): per (chunk c, col4) summaries with chunk-start M=0:
//   Bmu = local mu after CH steps, Te = sum e_i, See = sum a^{CH-1-i} e_i^2
// D2 (passWC): per (chunk c, col4):
//   walk: apply the chunk-transfer map for chunks 0..c-1 starting from
//         (m,var) — exactly the proven serial-passB algebra:
//           sum = See - 2*c_eg*M*Te + M^2*Sgg
//           V' = A*V + KCOEF*sum ;  M' = A*M + Bmu
//         The summary table is 6 MB total -> L2/L3-resident after D1;
//         reads are coalesced; redundancy across blocks is L2-served and
//         overlaps other blocks' HBM streaming.
//   replay: exact reference recurrence over chunk c; NT stores (proven R10)
//           so out doesn't evict x from L3 for the re-read.
// Removes vs R10: passBfused dispatch, one ~5us dispatch boundary, and the
// 8 MB Ms/Vs round-trip. No cross-block sync/atomics (those measured
// 0.9-3 TB/s in R4/R9/R11/R13).
// ===========================================================================

__global__ __launch_bounds__(256) void
passA(const float* __restrict__ x, float* __restrict__ Bmu,
      float* __restrict__ See, float* __restrict__ Te, int L4, int CH) {
  int idx  = blockIdx.x * blockDim.x + threadIdx.x;
  int col4 = idx % L4;
  int c    = idx / L4;
  const floatx4* xv = (const floatx4*)x;
  int base = c * CH * L4 + col4;

  float mu[4] = {0.f, 0.f, 0.f, 0.f};
  float s[4]  = {0.f, 0.f, 0.f, 0.f};
  float t[4]  = {0.f, 0.f, 0.f, 0.f};
#pragma unroll 4
  for (int i = 0; i < CH; ++i) {
    floatx4 v = xv[base + i * L4];
#pragma unroll
    for (int k = 0; k < 4; ++k) {
      float e = v[k] - mu[k];
      s[k] = fmaf(AFWD, s[k], e * e);
      t[k] += e;
      mu[k] = fmaf(ONE_MINUS_A, e, mu[k]);
    }
  }
  int o = c * L4 + col4;
  floatx4 om = {mu[0], mu[1], mu[2], mu[3]};
  floatx4 os = {s[0], s[1], s[2], s[3]};
  floatx4 ot = {t[0], t[1], t[2], t[3]};
  ((floatx4*)Bmu)[o] = om;
  ((floatx4*)See)[o] = os;
  ((floatx4*)Te)[o]  = ot;
}

__global__ __launch_bounds__(256) void
passWC(const float* __restrict__ x, const float* __restrict__ m,
       const float* __restrict__ var, const float* __restrict__ Bmu,
       const float* __restrict__ See, const float* __restrict__ Te,
       float* __restrict__ out, int L4, int CH,
       float A, float c_eg, float Sgg) {
  int idx  = blockIdx.x * blockDim.x + threadIdx.x;
  int col4 = idx % L4;
  int c    = idx / L4;
  const floatx4* xv   = (const floatx4*)x;
  const floatx4* bmu4 = (const floatx4*)Bmu;
  const floatx4* see4 = (const floatx4*)See;
  const floatx4* te4  = (const floatx4*)Te;
  floatx4* ov = (floatx4*)out;
  int base = c * CH * L4 + col4;

  // ---- walk: chunks 0..c-1 from (m,var); summaries are L2/L3-hot ----
  float M[4], V[4];
  {
    floatx4 m4 = ((const floatx4*)m)[col4];
    floatx4 v4 = ((const floatx4*)var)[col4];
#pragma unroll
    for (int k = 0; k < 4; ++k) { M[k] = m4[k]; V[k] = v4[k]; }
  }
#pragma unroll 4
  for (int cc = 0; cc < c; ++cc) {
    int o = cc * L4 + col4;
    floatx4 bb = bmu4[o];
    floatx4 ss = see4[o];
    floatx4 tt = te4[o];
#pragma unroll
    for (int k = 0; k < 4; ++k) {
      float sum = fmaf(M[k] * M[k], Sgg,
                       fmaf(-2.0f * c_eg * M[k], tt[k], ss[k]));
      V[k] = fmaf(A, V[k], KCOEF * sum);
      M[k] = fmaf(A, M[k], bb[k]);
    }
  }

  // ---- replay chunk c exactly; NT stores ----
#pragma unroll 4
  for (int i = 0; i < CH; ++i) {
    floatx4 v = xv[base + i * L4];
    floatx4 oe;
#pragma unroll
    for (int k = 0; k < 4; ++k) {
      float d = v[k] - M[k];
      oe[k] = d * rsqrtf(V[k] + EPSV);
      V[k] = fmaf(AFWD, V[k], KCOEF * (d * d));
      M[k] = fmaf(ONE_MINUS_A, d, M[k]);
    }
    __builtin_nontemporal_store(oe, &ov[base + i * L4]);
  }
}

extern "C" void kernel_launch(void* const* d_in, const int* in_sizes, int n_in,
                              void* d_out, int out_size, void* d_ws, size_t ws_size,
                              hipStream_t stream) {
  const float* x   = (const float*)d_in[0];
  const float* m   = (const float*)d_in[1];
  const float* var = (const float*)d_in[2];
  float* out = (float*)d_out;

  int L  = in_sizes[1];          // 4096
  int N  = in_sizes[0] / L;      // 8192
  int L4 = L / 4;

  int C = 128;
  while (C > 1 &&
         ((size_t)3 * C * L * sizeof(float) > ws_size || (N % C) != 0))
    C >>= 1;
  int CH = N / C;

  double a = 0.999;
  float A    = (float)pow(a, (double)CH);
  float c_eg = (float)pow(a, (double)(CH - 1));
  float Sgg  = (float)(pow(a, (double)(CH - 1)) * (1.0 - pow(a, (double)CH)) / (1.0 - a));

  float* ws  = (float*)d_ws;
  size_t CL  = (size_t)C * L;
  float* Bmu = ws;
  float* See = ws + CL;
  float* Te  = ws + 2 * CL;

  int gridBlocks = (C * L4) / 256;
  passA<<<gridBlocks, 256, 0, stream>>>(x, Bmu, See, Te, L4, CH);
  passWC<<<gridBlocks, 256, 0, stream>>>(x, m, var, Bmu, See, Te, out, L4, CH,
                                         A, c_eg, Sgg);
}

// Round 17
// 75.747 us; speedup vs baseline: 1.1257x; 1.1257x over previous
//
#include <hip/hip_runtime.h>
#include <math.h>

#define AFWD 0.999f
#define ONE_MINUS_A (1.0f - 0.999f)
#define KCOEF (0.999f * (1.0f - 0.999f))
#define EPSV 1e-5f

typedef float floatx4 __attribute__((ext_vector_type(4)));

// ---------------------------------------------------------------------------
// Pass A (exact R10): per (chunk c, col4) local summaries with chunk-start
// M=0. Bmu = local mu after CH steps, Te = sum e_i, See = sum a^{CH-1-i} e_i^2
// ---------------------------------------------------------------------------
__global__ __launch_bounds__(256) void
passA(const float* __restrict__ x, float* __restrict__ Bmu,
      float* __restrict__ See, float* __restrict__ Te, int L4, int CH) {
  int idx  = blockIdx.x * blockDim.x + threadIdx.x;
  int col4 = idx % L4;
  int c    = idx / L4;
  const floatx4* xv = (const floatx4*)x;
  int base = c * CH * L4 + col4;

  float mu[4] = {0.f, 0.f, 0.f, 0.f};
  float s[4]  = {0.f, 0.f, 0.f, 0.f};
  float t[4]  = {0.f, 0.f, 0.f, 0.f};
#pragma unroll 4
  for (int i = 0; i < CH; ++i) {
    floatx4 v = xv[base + i * L4];
#pragma unroll
    for (int k = 0; k < 4; ++k) {
      float e = v[k] - mu[k];
      s[k] = fmaf(AFWD, s[k], e * e);
      t[k] += e;
      mu[k] = fmaf(ONE_MINUS_A, e, mu[k]);
    }
  }
  int o = c * L4 + col4;
  floatx4 om = {mu[0], mu[1], mu[2], mu[3]};
  floatx4 os = {s[0], s[1], s[2], s[3]};
  floatx4 ot = {t[0], t[1], t[2], t[3]};
  ((floatx4*)Bmu)[o] = om;
  ((floatx4*)See)[o] = os;
  ((floatx4*)Te)[o]  = ot;
}

// ---------------------------------------------------------------------------
// Pass B (R10 algebra, narrower blocks): block = 128 threads = 8 supers x 16
// cols -> 256 blocks (1/CU coverage instead of 0.5/CU).
// ---------------------------------------------------------------------------
__global__ __launch_bounds__(128) void
passBfused(const float* __restrict__ m, const float* __restrict__ var,
           const float* __restrict__ Bmu, const float* __restrict__ See,
           const float* __restrict__ Te, float* __restrict__ Ms,
           float* __restrict__ Vs, int L, int SUB, int GS,
           float A, float c_eg, float Sgg, float G,
           float Asup, float c_sup, float Sggsup) {
  __shared__ float Bs[8][16], Ss[8][16], Ts[8][16];
  __shared__ float MgL[8][16], VgL[8][16];

  int g  = threadIdx.x >> 4;     // super slot [0,8)
  int lc = threadIdx.x & 15;     // col within block [0,16)
  int l  = blockIdx.x * 16 + lc;

  {
    int base = g * SUB * L + l;
    float B = 0.f, T = 0.f, S = 0.f;
#pragma unroll 4
    for (int k = 0; k < SUB; ++k) {
      int o = base + k * L;
      float b2 = Bmu[o];
      float s2 = See[o];
      float t2 = Te[o];
      S = fmaf(A, S, fmaf(Sgg * B, B, fmaf(-2.0f * c_eg * B, t2, s2)));
      T = fmaf(-G, B, T + t2);
      B = fmaf(A, B, b2);
    }
    Bs[g][lc] = B;
    Ss[g][lc] = S;
    Ts[g][lc] = T;
  }

  __syncthreads();

  if (threadIdx.x < 16) {
    float M = m[l];
    float V = var[l];
#pragma unroll
    for (int gg = 0; gg < 8; ++gg) {
      if (gg >= GS) break;
      MgL[gg][lc] = M;
      VgL[gg][lc] = V;
      float b = Bs[gg][lc];
      float s = Ss[gg][lc];
      float t = Ts[gg][lc];
      float sum = fmaf(M * M, Sggsup, fmaf(-2.0f * c_sup * M, t, s));
      V = fmaf(Asup, V, KCOEF * sum);
      M = fmaf(Asup, M, b);
    }
  }

  __syncthreads();

  {
    float M = MgL[g][lc];
    float V = VgL[g][lc];
    int base = g * SUB * L + l;
#pragma unroll 4
    for (int k = 0; k < SUB; ++k) {
      int o = base + k * L;
      Ms[o] = M;
      Vs[o] = V;
      float b = Bmu[o];
      float s = See[o];
      float t = Te[o];
      float sum = fmaf(M * M, Sgg, fmaf(-2.0f * c_eg * M, t, s));
      V = fmaf(A, V, KCOEF * sum);
      M = fmaf(A, M, b);
    }
  }
}

// ---------------------------------------------------------------------------
// Pass C: replay exact recurrence from (M_c, V_c).
// EXPERIMENT vs R10: normal (cached) stores instead of NT stores — the path
// the 7.16 TB/s fill kernel uses. Loads stay normal (x L3-resident).
// ---------------------------------------------------------------------------
__global__ __launch_bounds__(256) void
passC(const float* __restrict__ x, const float* __restrict__ Ms,
      const float* __restrict__ Vs, float* __restrict__ out, int L4, int CH) {
  int idx  = blockIdx.x * blockDim.x + threadIdx.x;
  int col4 = idx % L4;
  int c    = idx / L4;
  const floatx4* xv = (const floatx4*)x;
  floatx4* ov = (floatx4*)out;
  int base = c * CH * L4 + col4;

  int o = c * L4 + col4;
  floatx4 m4 = ((const floatx4*)Ms)[o];
  floatx4 v4 = ((const floatx4*)Vs)[o];
  float mu[4] = {m4[0], m4[1], m4[2], m4[3]};
  float vv[4] = {v4[0], v4[1], v4[2], v4[3]};
#pragma unroll 4
  for (int i = 0; i < CH; ++i) {
    floatx4 v = xv[base + i * L4];
    floatx4 oe;
#pragma unroll
    for (int k = 0; k < 4; ++k) {
      float d = v[k] - mu[k];
      oe[k] = d * rsqrtf(vv[k] + EPSV);
      vv[k] = fmaf(AFWD, vv[k], KCOEF * (d * d));
      mu[k] = fmaf(ONE_MINUS_A, d, mu[k]);
    }
    ov[base + i * L4] = oe;
  }
}

extern "C" void kernel_launch(void* const* d_in, const int* in_sizes, int n_in,
                              void* d_out, int out_size, void* d_ws, size_t ws_size,
                              hipStream_t stream) {
  const float* x   = (const float*)d_in[0];
  const float* m   = (const float*)d_in[1];
  const float* var = (const float*)d_in[2];
  float* out = (float*)d_out;

  int L  = in_sizes[1];          // 4096
  int N  = in_sizes[0] / L;      // 8192
  int L4 = L / 4;

  int C = 128;
  while (C > 1 &&
         ((size_t)5 * C * L * sizeof(float) > ws_size || (N % C) != 0))
    C >>= 1;
  int CH = N / C;
  int SUB = (C >= 16) ? 16 : C;
  int GS  = C / SUB;   // <= 8 for passBfused LDS

  double a = 0.999;
  float A    = (float)pow(a, (double)CH);
  float c_eg = (float)pow(a, (double)(CH - 1));
  float Sgg  = (float)(pow(a, (double)(CH - 1)) * (1.0 - pow(a, (double)CH)) / (1.0 - a));
  float G    = (float)((1.0 - pow(a, (double)CH)) / (1.0 - a));
  double nS = (double)SUB * CH;
  float Asup   = (float)pow(a, nS);
  float c_sup  = (float)pow(a, nS - 1.0);
  float Sggsup = (float)(pow(a, nS - 1.0) * (1.0 - pow(a, nS)) / (1.0 - a));

  float* ws  = (float*)d_ws;
  size_t CL  = (size_t)C * L;
  float* Bmu = ws;
  float* See = ws + CL;
  float* Te  = ws + 2 * CL;
  float* Ms  = ws + 3 * CL;
  float* Vs  = ws + 4 * CL;

  int gridBlocks = (C * L4) / 256;
  passA<<<gridBlocks, 256, 0, stream>>>(x, Bmu, See, Te, L4, CH);
  passBfused<<<L / 16, 128, 0, stream>>>(m, var, Bmu, See, Te, Ms, Vs, L,
                                         SUB, GS, A, c_eg, Sgg, G,
                                         Asup, c_sup, Sggsup);
  passC<<<gridBlocks, 256, 0, stream>>>(x, Ms, Vs, out, L4, CH);
}